// Round 5
// baseline (841.976 us; speedup 1.0000x reference)
//
#include <hip/hip_runtime.h>
#include <math.h>

#define NPIX 16384      // H*W
#define CCH  512        // channels
#define MS   262144     // 512*512

typedef unsigned short u16;
typedef unsigned int u32;
typedef __attribute__((ext_vector_type(8))) short bf16x8;   // 8 bf16 = 4 VGPR
typedef __attribute__((ext_vector_type(4))) float f32x4;

__device__ __forceinline__ u16 f2bf(float f) {
  u32 u = __builtin_bit_cast(u32, f);
  u += 0x7fffu + ((u >> 16) & 1u);    // round-to-nearest-even
  return (u16)(u >> 16);
}
__device__ __forceinline__ float b2f(u16 h) {
  u32 u = ((u32)h) << 16;
  return __builtin_bit_cast(float, u);
}

typedef const __attribute__((address_space(1))) u32* gp_t;
typedef __attribute__((address_space(3))) u32* lp_t;
__device__ __forceinline__ void gl_lds16(const void* g, void* l) {
  __builtin_amdgcn_global_load_lds((gp_t)g, (lp_t)l, 16, 0, 0);
}

// ---- Kt=128 staged tile, XOR chunk swizzle (LDS row = 128 bf16 = 16x16B chunks)
__device__ __forceinline__ void stage4(const u16* tile, size_t stride, int rl,
                                       int k0, u16* lds, int lane) {
  int lr = lane >> 4;                               // 4 rows per instruction
  int cg = (lane & 15) ^ ((rl + lr) & 15);          // swizzled global chunk
  gl_lds16(tile + (size_t)(rl + lr) * stride + k0 + cg * 8,
           lds + (size_t)rl * 128);
}
__device__ __forceinline__ bf16x8 fragld(const u16* lds, int row, int cl) {
  return *(const bf16x8*)&lds[(size_t)row * 128 + (size_t)((cl ^ (row & 15)) << 3)];
}

// ---- device-scope grid barrier (256 blocks, all resident at 1/CU)
__device__ __forceinline__ void gbar(u32* cnt, u32* gen) {
  __syncthreads();
  if (threadIdx.x == 0) {
    u32 g = __hip_atomic_load(gen, __ATOMIC_RELAXED, __HIP_MEMORY_SCOPE_AGENT);
    __threadfence();
    u32 old = __hip_atomic_fetch_add(cnt, 1u, __ATOMIC_ACQ_REL, __HIP_MEMORY_SCOPE_AGENT);
    if (old == 255u) {
      __hip_atomic_store(cnt, 0u, __ATOMIC_RELAXED, __HIP_MEMORY_SCOPE_AGENT);
      __hip_atomic_fetch_add(gen, 1u, __ATOMIC_RELEASE, __HIP_MEMORY_SCOPE_AGENT);
    } else {
      while (__hip_atomic_load(gen, __ATOMIC_ACQUIRE, __HIP_MEMORY_SCOPE_AGENT) == g)
        __builtin_amdgcn_s_sleep(8);
    }
    __threadfence();
  }
  __syncthreads();
}

// ================= prep: one pass over X -> colsums, fct (bf16 [c][n]), fcb (bf16 [n][c])
__global__ __launch_bounds__(256) void prep_k(const float* __restrict__ Xc,
                                              const float* __restrict__ Xs,
                                              float* __restrict__ sums,
                                              u16* __restrict__ fct,
                                              u16* __restrict__ fcb) {
  int b = blockIdx.z;
  const float* X = b ? Xs : Xc;
  u16* outT = fct + (size_t)b * ((size_t)CCH * NPIX);
  __shared__ float T[64][65];
  __shared__ float red2[64][4];
  int n0 = blockIdx.x * 64, c0 = blockIdx.y * 64;
  int t = threadIdx.x;
  int cr = t & 15, nr = t >> 4;
  #pragma unroll
  for (int rr = 0; rr < 4; ++rr) {
    int n = nr + rr * 16;
    float4 v = *(const float4*)&X[(size_t)(n0 + n) * CCH + c0 + cr * 4];
    T[n][cr * 4 + 0] = v.x;
    T[n][cr * 4 + 1] = v.y;
    T[n][cr * 4 + 2] = v.z;
    T[n][cr * 4 + 3] = v.w;
    if (b == 0) {
      ushort4 q;
      q.x = f2bf(v.x); q.y = f2bf(v.y); q.z = f2bf(v.z); q.w = f2bf(v.w);
      *(ushort4*)&fcb[(size_t)(n0 + n) * CCH + c0 + cr * 4] = q;
    }
  }
  __syncthreads();
  int cl = t >> 2, np = (t & 3) * 16;
  size_t obase = (size_t)(c0 + cl) * NPIX + n0 + np;
  float s = 0.f;
  #pragma unroll
  for (int i = 0; i < 16; i += 4) {
    float v0 = T[np + i + 0][cl], v1 = T[np + i + 1][cl];
    float v2 = T[np + i + 2][cl], v3 = T[np + i + 3][cl];
    s += v0 + v1 + v2 + v3;
    ushort4 o;
    o.x = f2bf(v0); o.y = f2bf(v1); o.z = f2bf(v2); o.w = f2bf(v3);
    *(ushort4*)&outT[obase + i] = o;
  }
  red2[cl][t & 3] = s;
  __syncthreads();
  if (t < 64) {
    float cs = red2[t][0] + red2[t][1] + red2[t][2] + red2[t][3];
    atomicAdd(&sums[b * CCH + c0 + t], cs);
  }
}

// ================= Gram: full 4x4 pairs x 16 kc x 2 batches = 512 blocks (2/CU)
// kc fastest-varying -> XCDs partition K (L2 locality).
__global__ __launch_bounds__(256) void gram_mfma(const u16* __restrict__ fct,
                                                 float* __restrict__ G) {
  int kc = blockIdx.x;               // 0..15, K chunk of 1024
  int pair = blockIdx.y;             // 0..15
  int b = blockIdx.z;
  int bi = pair >> 2, bj = pair & 3;
  const u16* Xb = fct + (size_t)b * ((size_t)CCH * NPIX);
  float* Gb = G + (size_t)b * MS;
  __shared__ u16 As[128 * 128];
  __shared__ u16 Bs[128 * 128];
  int tid = threadIdx.x, w = tid >> 6, lane = tid & 63;
  int qm = w & 1, qn = w >> 1;
  const u16* ssrc = (w < 2) ? Xb + (size_t)(bi * 128) * NPIX
                            : Xb + (size_t)(bj * 128) * NPIX;
  u16* sdst = (w < 2) ? As : Bs;
  int rbase = (w & 1) * 64;
  f32x4 acc[4][4];
  #pragma unroll
  for (int t = 0; t < 4; ++t)
    #pragma unroll
    for (int u = 0; u < 4; ++u) acc[t][u] = (f32x4)(0.f);

  for (int st = 0; st < 8; ++st) {
    int k0 = kc * 1024 + st * 128;
    __syncthreads();
    #pragma unroll
    for (int i = 0; i < 16; ++i) stage4(ssrc, NPIX, rbase + i * 4, k0, sdst, lane);
    __syncthreads();
    #pragma unroll
    for (int s = 0; s < 4; ++s) {
      int cl = s * 4 + (lane >> 4);
      bf16x8 a[4], bb[4];
      #pragma unroll
      for (int t = 0; t < 4; ++t) a[t] = fragld(As, qm * 64 + t * 16 + (lane & 15), cl);
      #pragma unroll
      for (int u = 0; u < 4; ++u) bb[u] = fragld(Bs, qn * 64 + u * 16 + (lane & 15), cl);
      #pragma unroll
      for (int t = 0; t < 4; ++t)
        #pragma unroll
        for (int u = 0; u < 4; ++u)
          acc[t][u] = __builtin_amdgcn_mfma_f32_16x16x32_bf16(a[t], bb[u], acc[t][u], 0, 0, 0);
    }
  }
  #pragma unroll
  for (int t = 0; t < 4; ++t) {
    int row0 = bi * 128 + qm * 64 + t * 16 + (lane >> 4) * 4;
    #pragma unroll
    for (int u = 0; u < 4; ++u) {
      int col = bj * 128 + qn * 64 + u * 16 + (lane & 15);
      #pragma unroll
      for (int r4 = 0; r4 < 4; ++r4)
        atomicAdd(&Gb[(size_t)(row0 + r4) * CCH + col], acc[t][u][r4]);
    }
  }
}

// ================= persistent kernel: cov -> ... -> mconst (15 global barriers)
struct PArgs {
  u32* cnt; u32* gen;
  float *sums, *rowsum, *G, *cov, *snorm, *coef, *mconst, *Zf;
  u16 *Anh, *Anl, *Y1, *Ya, *Z0, *Z1, *Tb;
  u16 *Zfsh, *Zfsl, *Ph, *Pl, *Qh, *Ql, *Zrsh, *Zrsl, *W2h, *W2l, *Mb;
};

// plain bf16 64x64 mm: D = diag*I + scale*(A @ B^T); outFp32 selects D type
__device__ void mm_job(const u16* A, const u16* B, void* D,
                       float scale, float diag, int outFp32,
                       int tj, int tid, u16* smem) {
  int bi = tj >> 3, bj = tj & 7;
  u16* As = smem;
  u16* Bs = smem + 8192;
  int w = tid >> 6, lane = tid & 63;
  int qm = w & 1, qn = w >> 1;
  const u16* ssrc = (w < 2) ? A + (size_t)(bi * 64) * CCH : B + (size_t)(bj * 64) * CCH;
  u16* sdst = (w < 2) ? As : Bs;
  int rbase = (w & 1) * 32;
  f32x4 acc[2][2];
  #pragma unroll
  for (int t = 0; t < 2; ++t)
    #pragma unroll
    for (int u = 0; u < 2; ++u) acc[t][u] = (f32x4)(0.f);

  for (int st = 0; st < 4; ++st) {
    int k0 = st * 128;
    __syncthreads();
    #pragma unroll
    for (int i = 0; i < 8; ++i) stage4(ssrc, CCH, rbase + i * 4, k0, sdst, lane);
    __syncthreads();
    #pragma unroll
    for (int s = 0; s < 4; ++s) {
      int cl = s * 4 + (lane >> 4);
      bf16x8 a[2], bb[2];
      #pragma unroll
      for (int t = 0; t < 2; ++t) a[t] = fragld(As, qm * 32 + t * 16 + (lane & 15), cl);
      #pragma unroll
      for (int u = 0; u < 2; ++u) bb[u] = fragld(Bs, qn * 32 + u * 16 + (lane & 15), cl);
      #pragma unroll
      for (int t = 0; t < 2; ++t)
        #pragma unroll
        for (int u = 0; u < 2; ++u)
          acc[t][u] = __builtin_amdgcn_mfma_f32_16x16x32_bf16(a[t], bb[u], acc[t][u], 0, 0, 0);
    }
  }
  #pragma unroll
  for (int t = 0; t < 2; ++t) {
    int row0 = bi * 64 + qm * 32 + t * 16 + (lane >> 4) * 4;
    #pragma unroll
    for (int u = 0; u < 2; ++u) {
      int col = bj * 64 + qn * 32 + u * 16 + (lane & 15);
      #pragma unroll
      for (int r4 = 0; r4 < 4; ++r4) {
        float v = scale * acc[t][u][r4];
        if (row0 + r4 == col) v += diag;
        size_t o = (size_t)(row0 + r4) * CCH + col;
        if (outFp32) ((float*)D)[o] = v;
        else ((u16*)D)[o] = f2bf(v);
      }
    }
  }
}

// split-bf16 64x64 mm: mode 0: split out; 1: fp32 out + beta*(Eh+El); 2: bf16 out
__device__ void mm_split_job(const u16* Ah, const u16* Al,
                             const u16* Bh, const u16* Bl,
                             const u16* Eh, const u16* El,
                             u16* Dh, u16* Dl, float* D32, u16* Db,
                             float scale, float beta, int mode,
                             int tj, int tid, u16* smem) {
  int bi = tj >> 3, bj = tj & 7;
  u16* Ash = smem;
  u16* Asl = smem + 8192;
  u16* Bsh = smem + 16384;
  u16* Bsl = smem + 24576;
  int w = tid >> 6, lane = tid & 63;
  int qm = w & 1, qn = w >> 1;
  const u16* sp = (w == 0) ? Ah : (w == 1) ? Al : (w == 2) ? Bh : Bl;
  const u16* ssrc = sp + (size_t)(((w < 2) ? bi : bj) * 64) * CCH;
  u16* sdst = (w == 0) ? Ash : (w == 1) ? Asl : (w == 2) ? Bsh : Bsl;
  f32x4 acc[2][2];
  #pragma unroll
  for (int t = 0; t < 2; ++t)
    #pragma unroll
    for (int u = 0; u < 2; ++u) acc[t][u] = (f32x4)(0.f);

  for (int st = 0; st < 4; ++st) {
    int k0 = st * 128;
    __syncthreads();
    #pragma unroll
    for (int i = 0; i < 16; ++i) stage4(ssrc, CCH, i * 4, k0, sdst, lane);
    __syncthreads();
    #pragma unroll
    for (int s = 0; s < 4; ++s) {
      int cl = s * 4 + (lane >> 4);
      bf16x8 ah[2], al[2], bh[2], bl[2];
      #pragma unroll
      for (int t = 0; t < 2; ++t) {
        int row = qm * 32 + t * 16 + (lane & 15);
        ah[t] = fragld(Ash, row, cl);
        al[t] = fragld(Asl, row, cl);
      }
      #pragma unroll
      for (int u = 0; u < 2; ++u) {
        int row = qn * 32 + u * 16 + (lane & 15);
        bh[u] = fragld(Bsh, row, cl);
        bl[u] = fragld(Bsl, row, cl);
      }
      #pragma unroll
      for (int t = 0; t < 2; ++t)
        #pragma unroll
        for (int u = 0; u < 2; ++u) {
          acc[t][u] = __builtin_amdgcn_mfma_f32_16x16x32_bf16(ah[t], bh[u], acc[t][u], 0, 0, 0);
          acc[t][u] = __builtin_amdgcn_mfma_f32_16x16x32_bf16(ah[t], bl[u], acc[t][u], 0, 0, 0);
          acc[t][u] = __builtin_amdgcn_mfma_f32_16x16x32_bf16(al[t], bh[u], acc[t][u], 0, 0, 0);
        }
    }
  }
  #pragma unroll
  for (int t = 0; t < 2; ++t) {
    int row0 = bi * 64 + qm * 32 + t * 16 + (lane >> 4) * 4;
    #pragma unroll
    for (int u = 0; u < 2; ++u) {
      int col = bj * 64 + qn * 32 + u * 16 + (lane & 15);
      #pragma unroll
      for (int r4 = 0; r4 < 4; ++r4) {
        size_t o = (size_t)(row0 + r4) * CCH + col;
        float v = scale * acc[t][u][r4];
        if (mode == 1) {
          v += beta * (b2f(Eh[o]) + b2f(El[o]));
          D32[o] = v;
        } else if (mode == 0) {
          u16 h = f2bf(v);
          Dh[o] = h;
          Dl[o] = f2bf(v - b2f(h));
        } else {
          Db[o] = f2bf(v);
        }
      }
    }
  }
}

__device__ void symsplit_step(const float* Zf, u16* hi, u16* lo, int blk, int tid) {
  #pragma unroll
  for (int e = 0; e < 8; ++e) {
    int idx = blk * 2048 + e * 256 + tid;
    int b = idx >> 18;
    int ij = idx & (MS - 1);
    int i = ij >> 9, j = ij & 511;
    size_t base = (size_t)b * MS;
    float v = 0.5f * (Zf[base + ij] + Zf[base + (size_t)j * CCH + i]);
    u16 h = f2bf(v);
    hi[base + ij] = h;
    lo[base + ij] = f2bf(v - b2f(h));
  }
}

__global__ __launch_bounds__(256) void persist_k(PArgs a) {
  __shared__ u16 smem[32768];   // 64 KB, aliased across steps
  float* red = (float*)smem;
  int tid = threadIdx.x, blk = blockIdx.x;
  const float invN = 1.f / (float)NPIX;
  const float invN1 = 1.f / (float)(NPIX - 1);

  // ---- step 1: cov = (G - s s^T/N)/(N-1) + eps I ; rowsum |.|  (4 rows/block)
  for (int rr = 0; rr < 4; ++rr) {
    int r = blk * 4 + rr;
    int b = r >> 9, i = r & 511;
    float si = a.sums[b * 512 + i];
    int j0 = tid * 2;
    float2 g = *(float2*)&a.G[(size_t)b * MS + (size_t)i * 512 + j0];
    float sj0 = a.sums[b * 512 + j0], sj1 = a.sums[b * 512 + j0 + 1];
    float v0 = (g.x - si * sj0 * invN) * invN1;
    float v1 = (g.y - si * sj1 * invN) * invN1;
    if (i == j0) v0 += 1e-8f;
    if (i == j0 + 1) v1 += 1e-8f;
    *(float2*)&a.cov[(size_t)b * MS + (size_t)i * 512 + j0] = make_float2(v0, v1);
    red[tid] = fabsf(v0) + fabsf(v1);
    __syncthreads();
    for (int s = 128; s > 0; s >>= 1) {
      if (tid < s) red[tid] += red[tid + s];
      __syncthreads();
    }
    if (tid == 0) a.rowsum[r] = red[0];
    __syncthreads();
  }
  gbar(a.cnt, a.gen);

  // ---- step 2: snorm (all blocks locally) + nsinit (+ fused first NS half-step)
  {
    float m = fmaxf(a.rowsum[tid], a.rowsum[tid + 256]);
    red[tid] = m; __syncthreads();
    for (int s = 128; s > 0; s >>= 1) {
      if (tid < s) red[tid] = fmaxf(red[tid], red[tid + s]);
      __syncthreads();
    }
    float snc = red[0]; __syncthreads();
    m = fmaxf(a.rowsum[512 + tid], a.rowsum[768 + tid]);
    red[tid] = m; __syncthreads();
    for (int s = 128; s > 0; s >>= 1) {
      if (tid < s) red[tid] = fmaxf(red[tid], red[tid + s]);
      __syncthreads();
    }
    float sns = red[0]; __syncthreads();
    if (blk == 0 && tid == 0) {
      a.snorm[0] = snc; a.snorm[1] = sns;
      a.coef[0] = 0.8f * sqrtf(sns / snc);
    }
    float inv0 = 1.f / snc, inv1 = 1.f / sns;
    #pragma unroll
    for (int e = 0; e < 8; ++e) {
      int idx = blk * 2048 + e * 256 + tid;
      int b = idx >> 18;
      int ij = idx & (MS - 1);
      int diag = (ij >> 9) == (ij & 511);
      float av = a.cov[idx] * (b ? inv1 : inv0);
      u16 hi = f2bf(av);
      a.Anh[idx] = hi;
      a.Anl[idx] = f2bf(av - b2f(hi));
      float t0 = (diag ? 3.f - av : -av) * 0.70710678f;  // boosted: c^2 = 2
      a.Z0[idx] = f2bf(t0);
    }
  }
  gbar(a.cnt, a.gen);

  // ---- NS chain (bf16).  y1: Y1 = Anh @ Z0
  if (blk < 128) {
    int jz = blk >> 6;
    mm_job(a.Anh + jz * MS, a.Z0 + jz * MS, a.Y1 + jz * MS, 1.f, 0.f, 0, blk & 63, tid, smem);
  }
  gbar(a.cnt, a.gen);
  // T0 = 3I - Z0 @ Y1
  if (blk < 128) {
    int jz = blk >> 6;
    mm_job(a.Z0 + jz * MS, a.Y1 + jz * MS, a.Tb + jz * MS, -1.f, 3.f, 0, blk & 63, tid, smem);
  }
  gbar(a.cnt, a.gen);
  // YZ0: Ya = Y1@T/2 ; Z1 = T@Z0/2
  {
    int jz = blk >> 6, b = jz & 1;
    if (jz < 2) mm_job(a.Y1 + b * MS, a.Tb + b * MS, a.Ya + b * MS, 0.5f, 0.f, 0, blk & 63, tid, smem);
    else        mm_job(a.Tb + b * MS, a.Z0 + b * MS, a.Z1 + b * MS, 0.5f, 0.f, 0, blk & 63, tid, smem);
  }
  gbar(a.cnt, a.gen);
  // T1 = 3I - Z1 @ Ya
  if (blk < 128) {
    int jz = blk >> 6;
    mm_job(a.Z1 + jz * MS, a.Ya + jz * MS, a.Tb + jz * MS, -1.f, 3.f, 0, blk & 63, tid, smem);
  }
  gbar(a.cnt, a.gen);
  // YZ1: Y1 = Ya@T/2 ; Z0 = T@Z1/2
  {
    int jz = blk >> 6, b = jz & 1;
    if (jz < 2) mm_job(a.Ya + b * MS, a.Tb + b * MS, a.Y1 + b * MS, 0.5f, 0.f, 0, blk & 63, tid, smem);
    else        mm_job(a.Tb + b * MS, a.Z1 + b * MS, a.Z0 + b * MS, 0.5f, 0.f, 0, blk & 63, tid, smem);
  }
  gbar(a.cnt, a.gen);
  // T2 = 3I - Z0 @ Y1
  if (blk < 128) {
    int jz = blk >> 6;
    mm_job(a.Z0 + jz * MS, a.Y1 + jz * MS, a.Tb + jz * MS, -1.f, 3.f, 0, blk & 63, tid, smem);
  }
  gbar(a.cnt, a.gen);
  // ZF = T2 @ Z0 / 2  (fp32)
  if (blk < 128) {
    int jz = blk >> 6;
    mm_job(a.Tb + jz * MS, a.Z0 + jz * MS, (void*)(a.Zf + (size_t)jz * MS), 0.5f, 0.f, 1, blk & 63, tid, smem);
  }
  gbar(a.cnt, a.gen);
  // symmetrize + split Zf
  symsplit_step(a.Zf, a.Zfsh, a.Zfsl, blk, tid);
  gbar(a.cnt, a.gen);
  // pq: P_b = Zfs_b @ An_b ; Q_b = Zfs_b @ Zfs_b   (split out)
  {
    int jz = blk >> 6, b = jz & 1, tj = blk & 63;
    if (jz < 2)
      mm_split_job(a.Zfsh + b * MS, a.Zfsl + b * MS, a.Anh + b * MS, a.Anl + b * MS,
                   0, 0, a.Ph + b * MS, a.Pl + b * MS, 0, 0, 1.f, 0.f, 0, tj, tid, smem);
    else
      mm_split_job(a.Zfsh + b * MS, a.Zfsl + b * MS, a.Zfsh + b * MS, a.Zfsl + b * MS,
                   0, 0, a.Qh + b * MS, a.Ql + b * MS, 0, 0, 1.f, 0.f, 0, tj, tid, smem);
  }
  gbar(a.cnt, a.gen);
  // zr: Zr_b = 1.5 Zfs_b - 0.5 P_b @ Q_b  (fp32 out into Zf)
  if (blk < 128) {
    int b = blk >> 6, tj = blk & 63;
    mm_split_job(a.Ph + b * MS, a.Pl + b * MS, a.Qh + b * MS, a.Ql + b * MS,
                 a.Zfsh + b * MS, a.Zfsl + b * MS, 0, 0, a.Zf + (size_t)b * MS, 0,
                 -0.5f, 1.5f, 1, tj, tid, smem);
  }
  gbar(a.cnt, a.gen);
  // symmetrize + split Zr
  symsplit_step(a.Zf, a.Zrsh, a.Zrsl, blk, tid);
  gbar(a.cnt, a.gen);
  // wv: W2 = An_s @ Zrs_s (split out)
  if (blk < 64) {
    mm_split_job(a.Anh + MS, a.Anl + MS, a.Zrsh + MS, a.Zrsl + MS,
                 0, 0, a.W2h, a.W2l, 0, 0, 1.f, 0.f, 0, blk, tid, smem);
  }
  gbar(a.cnt, a.gen);
  // mv: M = coef * W2 @ Zrs_c (bf16 out)
  if (blk < 64) {
    float cf = a.coef[0];
    mm_split_job(a.W2h, a.W2l, a.Zrsh, a.Zrsl,
                 0, 0, 0, 0, 0, a.Mb, cf, 0.f, 2, blk, tid, smem);
  }
  gbar(a.cnt, a.gen);
  // mconst[c] = 0.8*ms[c] - (M @ mc)[c]   (64 blocks x 8 c, 32 lanes per c)
  if (blk < 64) {
    int c = blk * 8 + (tid >> 5);
    int l = tid & 31;
    float s = 0.f;
    #pragma unroll
    for (int k = 0; k < 16; ++k) {
      int j = l + 32 * k;
      s += b2f(a.Mb[(size_t)c * CCH + j]) * a.sums[j];
    }
    s += __shfl_down(s, 16, 32);
    s += __shfl_down(s, 8, 32);
    s += __shfl_down(s, 4, 32);
    s += __shfl_down(s, 2, 32);
    s += __shfl_down(s, 1, 32);
    if (l == 0) a.mconst[c] = (0.8f * a.sums[512 + c] - s) * invN;
  }
}

// ================= apply: out = fcb @ M^T + mconst + 0.2 X   (128-tiles, Kt=128)
__global__ __launch_bounds__(256) void apply_mfma(const u16* __restrict__ fcb,
                                                  const u16* __restrict__ Mb,
                                                  const float* __restrict__ mconst,
                                                  const float* __restrict__ X,
                                                  float* __restrict__ out) {
  int bi = blockIdx.y;    // n tile (0..127)
  int bj = blockIdx.x;    // c tile (0..3)
  __shared__ u16 As[128 * 128];
  __shared__ u16 Bs[128 * 128];
  int tid = threadIdx.x, w = tid >> 6, lane = tid & 63;
  int qm = w & 1, qn = w >> 1;
  const u16* ssrc = (w < 2) ? fcb + (size_t)(bi * 128) * CCH
                            : Mb + (size_t)(bj * 128) * CCH;
  u16* sdst = (w < 2) ? As : Bs;
  int rbase = (w & 1) * 64;
  f32x4 acc[4][4];
  #pragma unroll
  for (int t = 0; t < 4; ++t)
    #pragma unroll
    for (int u = 0; u < 4; ++u) acc[t][u] = (f32x4)(0.f);

  for (int st = 0; st < 4; ++st) {
    int k0 = st * 128;
    __syncthreads();
    #pragma unroll
    for (int i = 0; i < 16; ++i) stage4(ssrc, CCH, rbase + i * 4, k0, sdst, lane);
    __syncthreads();
    #pragma unroll
    for (int s = 0; s < 4; ++s) {
      int cl = s * 4 + (lane >> 4);
      bf16x8 a[4], bb[4];
      #pragma unroll
      for (int t = 0; t < 4; ++t) a[t] = fragld(As, qm * 64 + t * 16 + (lane & 15), cl);
      #pragma unroll
      for (int u = 0; u < 4; ++u) bb[u] = fragld(Bs, qn * 64 + u * 16 + (lane & 15), cl);
      #pragma unroll
      for (int t = 0; t < 4; ++t)
        #pragma unroll
        for (int u = 0; u < 4; ++u)
          acc[t][u] = __builtin_amdgcn_mfma_f32_16x16x32_bf16(a[t], bb[u], acc[t][u], 0, 0, 0);
    }
  }
  #pragma unroll
  for (int t = 0; t < 4; ++t) {
    int row0 = bi * 128 + qm * 64 + t * 16 + (lane >> 4) * 4;
    #pragma unroll
    for (int u = 0; u < 4; ++u) {
      int col = bj * 128 + qn * 64 + u * 16 + (lane & 15);
      float cst = mconst[col];
      #pragma unroll
      for (int r4 = 0; r4 < 4; ++r4) {
        size_t o = (size_t)(row0 + r4) * CCH + col;
        out[o] = acc[t][u][r4] + cst + 0.2f * X[o];
      }
    }
  }
}

// ================================================================ launcher
extern "C" void kernel_launch(void* const* d_in, const int* in_sizes, int n_in,
                              void* d_out, int out_size, void* d_ws, size_t ws_size,
                              hipStream_t stream) {
  const float* Xc = (const float*)d_in[0];
  const float* Xs = (const float*)d_in[1];
  float* out = (float*)d_out;

  float* f = (float*)d_ws;
  u32* bar      = (u32*)f;               // [0]=cnt, [32]=gen (separate lines)
  float* sums   = f + 64;                // 1024
  float* rowsum = f + 64 + 1024;         // 1024
  float* G      = f + 64 + 2048;         // 2*MS
  float* cov    = G + 2 * MS;            // 2*MS
  float* snorm  = cov + 2 * MS;          // 8
  float* coef   = snorm + 8;             // 8
  float* mconst = coef + 8;              // 512
  float* Zf     = mconst + 512;          // 2*MS

  u16* h   = (u16*)(Zf + 2 * MS);
  u16* fct = h;                          // 2*512*16384 u16 (dead after gram)
  u16* fcb = h + (size_t)2 * CCH * NPIX; // 16384*512 u16
  const size_t B2 = 2 * MS;
  u16* Anh  = fct + 0 * B2;
  u16* Anl  = fct + 1 * B2;
  u16* Y1   = fct + 2 * B2;
  u16* Ya   = fct + 3 * B2;
  u16* Z0   = fct + 4 * B2;
  u16* Z1   = fct + 5 * B2;
  u16* Tb   = fct + 6 * B2;
  u16* Zfsh = fct + 7 * B2;
  u16* Zfsl = fct + 8 * B2;
  u16* Ph   = fct + 9 * B2;
  u16* Pl   = fct + 10 * B2;
  u16* Qh   = fct + 11 * B2;
  u16* Ql   = fct + 12 * B2;
  u16* Zrsh = fct + 13 * B2;
  u16* Zrsl = fct + 14 * B2;
  u16* W2h  = fct + 15 * B2;
  u16* W2l  = W2h + MS;
  u16* Mb   = W2l + MS;

  // zero: barrier words + sums + rowsum + G
  hipMemsetAsync(d_ws, 0, (64 + 2048 + 2 * MS) * sizeof(float), stream);

  prep_k<<<dim3(256, 8, 2), 256, 0, stream>>>(Xc, Xs, sums, fct, fcb);
  gram_mfma<<<dim3(16, 16, 2), 256, 0, stream>>>(fct, G);

  PArgs a;
  a.cnt = &bar[0]; a.gen = &bar[32];
  a.sums = sums; a.rowsum = rowsum; a.G = G; a.cov = cov;
  a.snorm = snorm; a.coef = coef; a.mconst = mconst; a.Zf = Zf;
  a.Anh = Anh; a.Anl = Anl; a.Y1 = Y1; a.Ya = Ya; a.Z0 = Z0; a.Z1 = Z1; a.Tb = Tb;
  a.Zfsh = Zfsh; a.Zfsl = Zfsl; a.Ph = Ph; a.Pl = Pl; a.Qh = Qh; a.Ql = Ql;
  a.Zrsh = Zrsh; a.Zrsl = Zrsl; a.W2h = W2h; a.W2l = W2l; a.Mb = Mb;
  persist_k<<<256, 256, 0, stream>>>(a);

  apply_mfma<<<dim3(4, 128), 256, 0, stream>>>(fcb, Mb, mconst, Xc, out);
}

// Round 6
// 320.350 us; speedup vs baseline: 2.6283x; 2.6283x over previous
//
#include <hip/hip_runtime.h>
#include <math.h>

#define NPIX 16384      // H*W
#define CCH  512        // channels
#define MS   262144     // 512*512

typedef unsigned short u16;
typedef unsigned int u32;
typedef __attribute__((ext_vector_type(8))) short bf16x8;   // 8 bf16 = 4 VGPR
typedef __attribute__((ext_vector_type(4))) float f32x4;

__device__ __forceinline__ u16 f2bf(float f) {
  u32 u = __builtin_bit_cast(u32, f);
  u += 0x7fffu + ((u >> 16) & 1u);    // round-to-nearest-even
  return (u16)(u >> 16);
}
__device__ __forceinline__ float b2f(u16 h) {
  u32 u = ((u32)h) << 16;
  return __builtin_bit_cast(float, u);
}

typedef const __attribute__((address_space(1))) u32* gp_t;
typedef __attribute__((address_space(3))) u32* lp_t;
__device__ __forceinline__ void gl_lds16(const void* g, void* l) {
  __builtin_amdgcn_global_load_lds((gp_t)g, (lp_t)l, 16, 0, 0);
}

// ---- Kt=128 staged tile, XOR chunk swizzle (LDS row = 128 bf16 = 16x16B chunks)
__device__ __forceinline__ void stage4(const u16* tile, size_t stride, int rl,
                                       int k0, u16* lds, int lane) {
  int lr = lane >> 4;                               // 4 rows per instruction
  int cg = (lane & 15) ^ ((rl + lr) & 15);          // swizzled global chunk
  gl_lds16(tile + (size_t)(rl + lr) * stride + k0 + cg * 8,
           lds + (size_t)rl * 128);
}
__device__ __forceinline__ bf16x8 fragld(const u16* lds, int row, int cl) {
  return *(const bf16x8*)&lds[(size_t)row * 128 + (size_t)((cl ^ (row & 15)) << 3)];
}

// ---- Kt=64 variants (LDS row = 64 bf16 = 8x16B chunks); 8 rows per gl_lds16
__device__ __forceinline__ void stage8_64(const u16* tile, size_t stride, int rl,
                                          int k0, u16* lds, int lane) {
  int lr = lane >> 3;                               // 8 rows per instruction
  int cg = (lane & 7) ^ ((rl + lr) & 7);            // swizzled global chunk
  gl_lds16(tile + (size_t)(rl + lr) * stride + k0 + cg * 8,
           lds + (size_t)rl * 64);
}
__device__ __forceinline__ bf16x8 fragld64(const u16* lds, int row, int cl) {
  return *(const bf16x8*)&lds[(size_t)row * 64 + (size_t)((cl ^ (row & 7)) << 3)];
}

// ================= prep: one pass over X -> colsums, fct (bf16 [c][n]), fcb (bf16 [n][c])
__global__ __launch_bounds__(256) void prep_k(const float* __restrict__ Xc,
                                              const float* __restrict__ Xs,
                                              float* __restrict__ sums,
                                              u16* __restrict__ fct,
                                              u16* __restrict__ fcb) {
  int b = blockIdx.z;
  const float* X = b ? Xs : Xc;
  u16* outT = fct + (size_t)b * ((size_t)CCH * NPIX);
  __shared__ float T[64][65];
  __shared__ float red2[64][4];
  int n0 = blockIdx.x * 64, c0 = blockIdx.y * 64;
  int t = threadIdx.x;
  int cr = t & 15, nr = t >> 4;
  #pragma unroll
  for (int rr = 0; rr < 4; ++rr) {
    int n = nr + rr * 16;
    float4 v = *(const float4*)&X[(size_t)(n0 + n) * CCH + c0 + cr * 4];
    T[n][cr * 4 + 0] = v.x;
    T[n][cr * 4 + 1] = v.y;
    T[n][cr * 4 + 2] = v.z;
    T[n][cr * 4 + 3] = v.w;
    if (b == 0) {
      ushort4 q;
      q.x = f2bf(v.x); q.y = f2bf(v.y); q.z = f2bf(v.z); q.w = f2bf(v.w);
      *(ushort4*)&fcb[(size_t)(n0 + n) * CCH + c0 + cr * 4] = q;
    }
  }
  __syncthreads();
  int cl = t >> 2, np = (t & 3) * 16;
  size_t obase = (size_t)(c0 + cl) * NPIX + n0 + np;
  float s = 0.f;
  #pragma unroll
  for (int i = 0; i < 16; i += 4) {
    float v0 = T[np + i + 0][cl], v1 = T[np + i + 1][cl];
    float v2 = T[np + i + 2][cl], v3 = T[np + i + 3][cl];
    s += v0 + v1 + v2 + v3;
    ushort4 o;
    o.x = f2bf(v0); o.y = f2bf(v1); o.z = f2bf(v2); o.w = f2bf(v3);
    *(ushort4*)&outT[obase + i] = o;
  }
  red2[cl][t & 3] = s;
  __syncthreads();
  if (t < 64) {
    float cs = red2[t][0] + red2[t][1] + red2[t][2] + red2[t][3];
    atomicAdd(&sums[b * CCH + c0 + t], cs);
  }
}

// ================= Gram: 16 pairs x 32 kc x 2 batches = 1024 blocks = 4/CU
// Kt=64 stages (32 KB LDS); kc fastest-varying -> XCDs partition K.
__global__ __launch_bounds__(256, 4) void gram_mfma(const u16* __restrict__ fct,
                                                    float* __restrict__ G) {
  int kc = blockIdx.x;               // 0..31, K chunk of 512
  int pair = blockIdx.y;             // 0..15
  int b = blockIdx.z;
  int bi = pair >> 2, bj = pair & 3;
  const u16* Xb = fct + (size_t)b * ((size_t)CCH * NPIX);
  float* Gb = G + (size_t)b * MS;
  __shared__ u16 As[128 * 64];       // 16 KB
  __shared__ u16 Bs[128 * 64];       // 16 KB
  int tid = threadIdx.x, w = tid >> 6, lane = tid & 63;
  int qm = w & 1, qn = w >> 1;
  const u16* ssrc = (w < 2) ? Xb + (size_t)(bi * 128) * NPIX
                            : Xb + (size_t)(bj * 128) * NPIX;
  u16* sdst = (w < 2) ? As : Bs;
  int rbase = (w & 1) * 64;
  f32x4 acc[4][4];
  #pragma unroll
  for (int t = 0; t < 4; ++t)
    #pragma unroll
    for (int u = 0; u < 4; ++u) acc[t][u] = (f32x4)(0.f);

  for (int st = 0; st < 8; ++st) {
    int k0 = kc * 512 + st * 64;
    __syncthreads();
    #pragma unroll
    for (int i = 0; i < 8; ++i) stage8_64(ssrc, NPIX, rbase + i * 8, k0, sdst, lane);
    __syncthreads();
    #pragma unroll
    for (int s = 0; s < 2; ++s) {
      int cl = s * 4 + (lane >> 4);
      bf16x8 a[4], bb[4];
      #pragma unroll
      for (int t = 0; t < 4; ++t) a[t] = fragld64(As, qm * 64 + t * 16 + (lane & 15), cl);
      #pragma unroll
      for (int u = 0; u < 4; ++u) bb[u] = fragld64(Bs, qn * 64 + u * 16 + (lane & 15), cl);
      #pragma unroll
      for (int t = 0; t < 4; ++t)
        #pragma unroll
        for (int u = 0; u < 4; ++u)
          acc[t][u] = __builtin_amdgcn_mfma_f32_16x16x32_bf16(a[t], bb[u], acc[t][u], 0, 0, 0);
    }
  }
  #pragma unroll
  for (int t = 0; t < 4; ++t) {
    int row0 = bi * 128 + qm * 64 + t * 16 + (lane >> 4) * 4;
    #pragma unroll
    for (int u = 0; u < 4; ++u) {
      int col = bj * 128 + qn * 64 + u * 16 + (lane & 15);
      #pragma unroll
      for (int r4 = 0; r4 < 4; ++r4)
        atomicAdd(&Gb[(size_t)(row0 + r4) * CCH + col], acc[t][u][r4]);
    }
  }
}

// ================= cov = (G - s s^T/N)/(N-1) + eps I ; rowsum |.| atomics
__global__ __launch_bounds__(256) void cov_k(const float* __restrict__ G,
                                             const float* __restrict__ sums,
                                             float* __restrict__ cov,
                                             float* __restrict__ rowsum) {
  int idx = blockIdx.x * 256 + threadIdx.x;   // 0 .. 2*MS-1
  int b = idx >> 18;
  int ij = idx & (MS - 1);
  int i = ij >> 9, j = ij & 511;
  const float* s = sums + b * CCH;
  float v = (G[idx] - s[i] * s[j] * (1.f / (float)NPIX)) * (1.f / (float)(NPIX - 1));
  if (i == j) v += 1e-8f;
  cov[idx] = v;
  __shared__ float red[256];
  int t = threadIdx.x;
  red[t] = fabsf(v);
  __syncthreads();
  for (int st = 128; st > 0; st >>= 1) {
    if (t < st) red[t] += red[t + st];
    __syncthreads();
  }
  if (t == 0) atomicAdd(&rowsum[b * CCH + i], red[0]);
}

// ================= NS init (+ fused norm/coef): An split; Z0 = (c/2)(3I-Â), c^2=2
__global__ __launch_bounds__(256) void nsinit_k(const float* __restrict__ cov,
                                                const float* __restrict__ rowsum,
                                                float* __restrict__ snorm,
                                                float* __restrict__ coef,
                                                u16* __restrict__ Anh,
                                                u16* __restrict__ Anl,
                                                u16* __restrict__ Z0) {
  __shared__ float red[256];
  int tid = threadIdx.x, blk = blockIdx.x;
  float m = fmaxf(rowsum[tid], rowsum[tid + 256]);
  red[tid] = m; __syncthreads();
  for (int s = 128; s > 0; s >>= 1) {
    if (tid < s) red[tid] = fmaxf(red[tid], red[tid + s]);
    __syncthreads();
  }
  float snc = red[0]; __syncthreads();
  m = fmaxf(rowsum[512 + tid], rowsum[768 + tid]);
  red[tid] = m; __syncthreads();
  for (int s = 128; s > 0; s >>= 1) {
    if (tid < s) red[tid] = fmaxf(red[tid], red[tid + s]);
    __syncthreads();
  }
  float sns = red[0];
  if (blk == 0 && tid == 0) {
    snorm[0] = snc; snorm[1] = sns;
    coef[0] = 0.8f * sqrtf(sns / snc);
  }
  int idx = blk * 256 + tid;                 // 0 .. 2*MS-1 (grid 2048)
  int b = idx >> 18;
  int ij = idx & (MS - 1);
  int diag = (ij >> 9) == (ij & 511);
  float av = cov[idx] * (b ? 1.f / sns : 1.f / snc);
  u16 hi = f2bf(av);
  Anh[idx] = hi;
  Anl[idx] = f2bf(av - b2f(hi));
  float t0 = (diag ? 3.f - av : -av) * 0.70710678f;   // boosted first step
  Z0[idx] = f2bf(t0);
}

// ================= plain bf16 NS matmul, 64x64 tiles, Kt=128: D = diag*I + scale*(A @ B^T)
struct MM16 {
  const u16* A[4];
  const u16* B[4];
  void* D[4];
  float scale, diag;
  int outFp32;
};

__global__ __launch_bounds__(256) void mm16_k(MM16 args) {
  int z = blockIdx.z;
  const u16* __restrict__ A = args.A[z];
  const u16* __restrict__ B = args.B[z];
  int bi = blockIdx.y, bj = blockIdx.x;
  __shared__ u16 As[64 * 128];
  __shared__ u16 Bs[64 * 128];
  int tid = threadIdx.x, w = tid >> 6, lane = tid & 63;
  int qm = w & 1, qn = w >> 1;
  const u16* ssrc = ((w < 2) ? A + (size_t)(bi * 64) * CCH : B + (size_t)(bj * 64) * CCH);
  u16* sdst = (w < 2) ? As : Bs;
  int rbase = (w & 1) * 32;
  f32x4 acc[2][2];
  #pragma unroll
  for (int t = 0; t < 2; ++t)
    #pragma unroll
    for (int u = 0; u < 2; ++u) acc[t][u] = (f32x4)(0.f);

  for (int st = 0; st < 4; ++st) {
    int k0 = st * 128;
    __syncthreads();
    #pragma unroll
    for (int i = 0; i < 8; ++i) stage4(ssrc, CCH, rbase + i * 4, k0, sdst, lane);
    __syncthreads();
    #pragma unroll
    for (int s = 0; s < 4; ++s) {
      int cl = s * 4 + (lane >> 4);
      bf16x8 a[2], bb[2];
      #pragma unroll
      for (int t = 0; t < 2; ++t) a[t] = fragld(As, qm * 32 + t * 16 + (lane & 15), cl);
      #pragma unroll
      for (int u = 0; u < 2; ++u) bb[u] = fragld(Bs, qn * 32 + u * 16 + (lane & 15), cl);
      #pragma unroll
      for (int t = 0; t < 2; ++t)
        #pragma unroll
        for (int u = 0; u < 2; ++u)
          acc[t][u] = __builtin_amdgcn_mfma_f32_16x16x32_bf16(a[t], bb[u], acc[t][u], 0, 0, 0);
    }
  }
  float sc = args.scale;
  #pragma unroll
  for (int t = 0; t < 2; ++t) {
    int row0 = bi * 64 + qm * 32 + t * 16 + (lane >> 4) * 4;
    #pragma unroll
    for (int u = 0; u < 2; ++u) {
      int col = bj * 64 + qn * 32 + u * 16 + (lane & 15);
      #pragma unroll
      for (int r4 = 0; r4 < 4; ++r4) {
        float v = sc * acc[t][u][r4];
        if (row0 + r4 == col) v += args.diag;
        size_t o = (size_t)(row0 + r4) * CCH + col;
        if (args.outFp32) ((float*)args.D[z])[o] = v;
        else ((u16*)args.D[z])[o] = f2bf(v);
      }
    }
  }
}

// ================= symmetrize + split fp32 -> hi/lo bf16
__global__ __launch_bounds__(256) void symsplit_k(const float* __restrict__ src,
                                                  u16* __restrict__ hi,
                                                  u16* __restrict__ lo) {
  int b = blockIdx.y;
  int ij = blockIdx.x * 256 + threadIdx.x;   // 0..MS-1
  int i = ij >> 9, j = ij & 511;
  size_t base = (size_t)b * MS;
  float v = 0.5f * (src[base + ij] + src[base + (size_t)j * CCH + i]);
  u16 h = f2bf(v);
  hi[base + ij] = h;
  lo[base + ij] = f2bf(v - b2f(h));
}

// ================= split-bf16 matmul (~fp32 quality), 64x64 tiles, Kt=128
struct MMS {
  const u16 *Ah[4], *Al[4], *Bh[4], *Bl[4];
  const u16 *Eh[4], *El[4];
  u16 *Dh[4], *Dl[4];
  float *D32[4];
  u16 *Db[4];
  float scale, beta;
  const float* coefPtr;
};

__global__ __launch_bounds__(256) void mmsplit_k(MMS args) {
  int z = blockIdx.z;
  int bi = blockIdx.y, bj = blockIdx.x;
  __shared__ u16 Ash[64 * 128], Asl[64 * 128], Bsh[64 * 128], Bsl[64 * 128];
  int tid = threadIdx.x, w = tid >> 6, lane = tid & 63;
  int qm = w & 1, qn = w >> 1;
  const u16* sp = (w == 0) ? args.Ah[z] : (w == 1) ? args.Al[z]
                : (w == 2) ? args.Bh[z] : args.Bl[z];
  const u16* ssrc = sp + (size_t)(((w < 2) ? bi : bj) * 64) * CCH;
  u16* sdst = (w == 0) ? Ash : (w == 1) ? Asl : (w == 2) ? Bsh : Bsl;
  f32x4 acc[2][2];
  #pragma unroll
  for (int t = 0; t < 2; ++t)
    #pragma unroll
    for (int u = 0; u < 2; ++u) acc[t][u] = (f32x4)(0.f);

  for (int st = 0; st < 4; ++st) {
    int k0 = st * 128;
    __syncthreads();
    #pragma unroll
    for (int i = 0; i < 16; ++i) stage4(ssrc, CCH, i * 4, k0, sdst, lane);
    __syncthreads();
    #pragma unroll
    for (int s = 0; s < 4; ++s) {
      int cl = s * 4 + (lane >> 4);
      bf16x8 ah[2], al[2], bh[2], bl[2];
      #pragma unroll
      for (int t = 0; t < 2; ++t) {
        int row = qm * 32 + t * 16 + (lane & 15);
        ah[t] = fragld(Ash, row, cl);
        al[t] = fragld(Asl, row, cl);
      }
      #pragma unroll
      for (int u = 0; u < 2; ++u) {
        int row = qn * 32 + u * 16 + (lane & 15);
        bh[u] = fragld(Bsh, row, cl);
        bl[u] = fragld(Bsl, row, cl);
      }
      #pragma unroll
      for (int t = 0; t < 2; ++t)
        #pragma unroll
        for (int u = 0; u < 2; ++u) {
          acc[t][u] = __builtin_amdgcn_mfma_f32_16x16x32_bf16(ah[t], bh[u], acc[t][u], 0, 0, 0);
          acc[t][u] = __builtin_amdgcn_mfma_f32_16x16x32_bf16(ah[t], bl[u], acc[t][u], 0, 0, 0);
          acc[t][u] = __builtin_amdgcn_mfma_f32_16x16x32_bf16(al[t], bh[u], acc[t][u], 0, 0, 0);
        }
    }
  }
  float sc = args.scale;
  if (args.coefPtr) sc *= *args.coefPtr;
  #pragma unroll
  for (int t = 0; t < 2; ++t) {
    int row0 = bi * 64 + qm * 32 + t * 16 + (lane >> 4) * 4;
    #pragma unroll
    for (int u = 0; u < 2; ++u) {
      int col = bj * 64 + qn * 32 + u * 16 + (lane & 15);
      #pragma unroll
      for (int r4 = 0; r4 < 4; ++r4) {
        size_t o = (size_t)(row0 + r4) * CCH + col;
        float v = sc * acc[t][u][r4];
        if (args.beta != 0.f) v += args.beta * (b2f(args.Eh[z][o]) + b2f(args.El[z][o]));
        if (args.D32[z]) args.D32[z][o] = v;
        if (args.Dh[z]) {
          u16 h = f2bf(v);
          args.Dh[z][o] = h;
          args.Dl[z][o] = f2bf(v - b2f(h));
        }
        if (args.Db[z]) args.Db[z][o] = f2bf(v);
      }
    }
  }
}

// ================= mconst[c] = (0.8*ssum[c] - (M @ csum)[c]) / N
__global__ __launch_bounds__(256) void mconst_k(const u16* __restrict__ Mb,
                                                const float* __restrict__ sums,
                                                float* __restrict__ mconst) {
  int c = blockIdx.x * 8 + (threadIdx.x >> 5);   // grid 64
  int l = threadIdx.x & 31;
  float s = 0.f;
  #pragma unroll
  for (int k = 0; k < 16; ++k) {
    int j = l + 32 * k;
    s += b2f(Mb[(size_t)c * CCH + j]) * sums[j];
  }
  s += __shfl_down(s, 16, 32);
  s += __shfl_down(s, 8, 32);
  s += __shfl_down(s, 4, 32);
  s += __shfl_down(s, 2, 32);
  s += __shfl_down(s, 1, 32);
  if (l == 0) mconst[c] = (0.8f * sums[512 + c] - s) * (1.f / (float)NPIX);
}

// ================= apply: out = fcb @ M^T + mconst + 0.2 X   (128-tiles, Kt=128)
__global__ __launch_bounds__(256) void apply_mfma(const u16* __restrict__ fcb,
                                                  const u16* __restrict__ Mb,
                                                  const float* __restrict__ mconst,
                                                  const float* __restrict__ X,
                                                  float* __restrict__ out) {
  int bi = blockIdx.y;    // n tile (0..127)
  int bj = blockIdx.x;    // c tile (0..3)
  __shared__ u16 As[128 * 128];
  __shared__ u16 Bs[128 * 128];
  int tid = threadIdx.x, w = tid >> 6, lane = tid & 63;
  int qm = w & 1, qn = w >> 1;
  const u16* ssrc = (w < 2) ? fcb + (size_t)(bi * 128) * CCH
                            : Mb + (size_t)(bj * 128) * CCH;
  u16* sdst = (w < 2) ? As : Bs;
  int rbase = (w & 1) * 64;
  f32x4 acc[4][4];
  #pragma unroll
  for (int t = 0; t < 4; ++t)
    #pragma unroll
    for (int u = 0; u < 4; ++u) acc[t][u] = (f32x4)(0.f);

  for (int st = 0; st < 4; ++st) {
    int k0 = st * 128;
    __syncthreads();
    #pragma unroll
    for (int i = 0; i < 16; ++i) stage4(ssrc, CCH, rbase + i * 4, k0, sdst, lane);
    __syncthreads();
    #pragma unroll
    for (int s = 0; s < 4; ++s) {
      int cl = s * 4 + (lane >> 4);
      bf16x8 a[4], bb[4];
      #pragma unroll
      for (int t = 0; t < 4; ++t) a[t] = fragld(As, qm * 64 + t * 16 + (lane & 15), cl);
      #pragma unroll
      for (int u = 0; u < 4; ++u) bb[u] = fragld(Bs, qn * 64 + u * 16 + (lane & 15), cl);
      #pragma unroll
      for (int t = 0; t < 4; ++t)
        #pragma unroll
        for (int u = 0; u < 4; ++u)
          acc[t][u] = __builtin_amdgcn_mfma_f32_16x16x32_bf16(a[t], bb[u], acc[t][u], 0, 0, 0);
    }
  }
  #pragma unroll
  for (int t = 0; t < 4; ++t) {
    int row0 = bi * 128 + qm * 64 + t * 16 + (lane >> 4) * 4;
    #pragma unroll
    for (int u = 0; u < 4; ++u) {
      int col = bj * 128 + qn * 64 + u * 16 + (lane & 15);
      float cst = mconst[col];
      #pragma unroll
      for (int r4 = 0; r4 < 4; ++r4) {
        size_t o = (size_t)(row0 + r4) * CCH + col;
        out[o] = acc[t][u][r4] + cst + 0.2f * X[o];
      }
    }
  }
}

// ================================================================ launcher
extern "C" void kernel_launch(void* const* d_in, const int* in_sizes, int n_in,
                              void* d_out, int out_size, void* d_ws, size_t ws_size,
                              hipStream_t stream) {
  const float* Xc = (const float*)d_in[0];
  const float* Xs = (const float*)d_in[1];
  float* out = (float*)d_out;

  float* f = (float*)d_ws;
  float* sums   = f;                     // 1024
  float* rowsum = f + 1024;              // 1024
  float* G      = f + 2048;              // 2*MS
  float* cov    = G + 2 * MS;            // 2*MS
  float* snorm  = cov + 2 * MS;          // 8
  float* coef   = snorm + 8;             // 8
  float* mconst = coef + 8;              // 512
  float* Zf     = mconst + 512;          // 2*MS (fp32, reused for Zr)

  u16* h   = (u16*)(Zf + 2 * MS);
  u16* fct = h;                          // 2*512*16384 u16 (dead after gram)
  u16* fcb = h + (size_t)2 * CCH * NPIX; // 16384*512 u16
  const size_t B2 = 2 * MS;
  u16* Anh  = fct + 0 * B2;
  u16* Anl  = fct + 1 * B2;
  u16* Y1   = fct + 2 * B2;
  u16* Ya   = fct + 3 * B2;
  u16* Z0   = fct + 4 * B2;
  u16* Z1   = fct + 5 * B2;
  u16* Tb   = fct + 6 * B2;
  u16* Zfsh = fct + 7 * B2;
  u16* Zfsl = fct + 8 * B2;
  u16* Ph   = fct + 9 * B2;
  u16* Pl   = fct + 10 * B2;
  u16* Qh   = fct + 11 * B2;
  u16* Ql   = fct + 12 * B2;
  u16* Zrsh = fct + 13 * B2;
  u16* Zrsl = fct + 14 * B2;
  u16* W2h  = fct + 15 * B2;
  u16* W2l  = W2h + MS;
  u16* Mb   = W2l + MS;

  // zero: sums + rowsum + G (contiguous)
  hipMemsetAsync(d_ws, 0, (2048 + 2 * MS) * sizeof(float), stream);

  prep_k<<<dim3(256, 8, 2), 256, 0, stream>>>(Xc, Xs, sums, fct, fcb);
  gram_mfma<<<dim3(32, 16, 2), 256, 0, stream>>>(fct, G);
  cov_k<<<2048, 256, 0, stream>>>(G, sums, cov, rowsum);
  nsinit_k<<<2048, 256, 0, stream>>>(cov, rowsum, snorm, coef, Anh, Anl, Z0);

  // NS: boosted first step (in nsinit) + 2 full iterations + final Z-update
  {
    MM16 y1{};
    y1.A[0] = Anh;      y1.B[0] = Z0;      y1.D[0] = Y1;
    y1.A[1] = Anh + MS; y1.B[1] = Z0 + MS; y1.D[1] = Y1 + MS;
    y1.scale = 1.f; y1.diag = 0.f; y1.outFp32 = 0;
    mm16_k<<<dim3(8, 8, 2), 256, 0, stream>>>(y1);
  }
  {
    MM16 t{};   // T0 = 3I - Z0 @ Y1
    t.A[0] = Z0;      t.B[0] = Y1;      t.D[0] = Tb;
    t.A[1] = Z0 + MS; t.B[1] = Y1 + MS; t.D[1] = Tb + MS;
    t.scale = -1.f; t.diag = 3.f; t.outFp32 = 0;
    mm16_k<<<dim3(8, 8, 2), 256, 0, stream>>>(t);
  }
  {
    MM16 yz{};  // Ya = Y1@T0/2 ; Z1 = T0@Z0/2
    yz.A[0] = Y1;      yz.B[0] = Tb;      yz.D[0] = Ya;
    yz.A[1] = Y1 + MS; yz.B[1] = Tb + MS; yz.D[1] = Ya + MS;
    yz.A[2] = Tb;      yz.B[2] = Z0;      yz.D[2] = Z1;
    yz.A[3] = Tb + MS; yz.B[3] = Z0 + MS; yz.D[3] = Z1 + MS;
    yz.scale = 0.5f; yz.diag = 0.f; yz.outFp32 = 0;
    mm16_k<<<dim3(8, 8, 4), 256, 0, stream>>>(yz);
  }
  {
    MM16 t{};   // T1 = 3I - Z1 @ Ya
    t.A[0] = Z1;      t.B[0] = Ya;      t.D[0] = Tb;
    t.A[1] = Z1 + MS; t.B[1] = Ya + MS; t.D[1] = Tb + MS;
    t.scale = -1.f; t.diag = 3.f; t.outFp32 = 0;
    mm16_k<<<dim3(8, 8, 2), 256, 0, stream>>>(t);
  }
  {
    MM16 yz{};  // Y1 = Ya@T1/2 ; Z0 = T1@Z1/2
    yz.A[0] = Ya;      yz.B[0] = Tb;      yz.D[0] = Y1;
    yz.A[1] = Ya + MS; yz.B[1] = Tb + MS; yz.D[1] = Y1 + MS;
    yz.A[2] = Tb;      yz.B[2] = Z1;      yz.D[2] = Z0;
    yz.A[3] = Tb + MS; yz.B[3] = Z1 + MS; yz.D[3] = Z0 + MS;
    yz.scale = 0.5f; yz.diag = 0.f; yz.outFp32 = 0;
    mm16_k<<<dim3(8, 8, 4), 256, 0, stream>>>(yz);
  }
  {
    MM16 t{};   // T2 = 3I - Z0 @ Y1
    t.A[0] = Z0;      t.B[0] = Y1;      t.D[0] = Tb;
    t.A[1] = Z0 + MS; t.B[1] = Y1 + MS; t.D[1] = Tb + MS;
    t.scale = -1.f; t.diag = 3.f; t.outFp32 = 0;
    mm16_k<<<dim3(8, 8, 2), 256, 0, stream>>>(t);
  }
  {
    MM16 zf{};  // Zf = T2 @ Z0 / 2  (fp32)
    zf.A[0] = Tb;      zf.B[0] = Z0;      zf.D[0] = Zf;
    zf.A[1] = Tb + MS; zf.B[1] = Z0 + MS; zf.D[1] = Zf + MS;
    zf.scale = 0.5f; zf.diag = 0.f; zf.outFp32 = 1;
    mm16_k<<<dim3(8, 8, 2), 256, 0, stream>>>(zf);
  }

  // symmetrize+split Zf
  symsplit_k<<<dim3(1024, 2), 256, 0, stream>>>(Zf, Zfsh, Zfsl);

  // P_b = Zfs_b @ An_b ; Q_b = Zfs_b @ Zfs_b
  MMS pq{};
  for (int b = 0; b < 2; ++b) {
    pq.Ah[b] = Zfsh + b * MS; pq.Al[b] = Zfsl + b * MS;
    pq.Bh[b] = Anh + b * MS;  pq.Bl[b] = Anl + b * MS;
    pq.Dh[b] = Ph + b * MS;   pq.Dl[b] = Pl + b * MS;
    pq.Ah[2 + b] = Zfsh + b * MS; pq.Al[2 + b] = Zfsl + b * MS;
    pq.Bh[2 + b] = Zfsh + b * MS; pq.Bl[2 + b] = Zfsl + b * MS;
    pq.Dh[2 + b] = Qh + b * MS;   pq.Dl[2 + b] = Ql + b * MS;
  }
  pq.scale = 1.f;
  mmsplit_k<<<dim3(8, 8, 4), 256, 0, stream>>>(pq);

  // Zr_b = 1.5 Zfs_b - 0.5 P_b @ Q_b  (fp32 out into Zf)
  MMS zr{};
  for (int b = 0; b < 2; ++b) {
    zr.Ah[b] = Ph + b * MS;   zr.Al[b] = Pl + b * MS;
    zr.Bh[b] = Qh + b * MS;   zr.Bl[b] = Ql + b * MS;
    zr.Eh[b] = Zfsh + b * MS; zr.El[b] = Zfsl + b * MS;
    zr.D32[b] = Zf + b * MS;
  }
  zr.scale = -0.5f; zr.beta = 1.5f;
  mmsplit_k<<<dim3(8, 8, 2), 256, 0, stream>>>(zr);

  // symmetrize+split Zr
  symsplit_k<<<dim3(1024, 2), 256, 0, stream>>>(Zf, Zrsh, Zrsl);

  // W2 = An_s @ Zrs_s (split out)
  MMS wv{};
  wv.Ah[0] = Anh + MS;  wv.Al[0] = Anl + MS;
  wv.Bh[0] = Zrsh + MS; wv.Bl[0] = Zrsl + MS;
  wv.Dh[0] = W2h; wv.Dl[0] = W2l;
  wv.scale = 1.f;
  mmsplit_k<<<dim3(8, 8, 1), 256, 0, stream>>>(wv);

  // M = coef * W2 @ Zrs_c (bf16 out)
  MMS mv{};
  mv.Ah[0] = W2h;  mv.Al[0] = W2l;
  mv.Bh[0] = Zrsh; mv.Bl[0] = Zrsl;
  mv.Db[0] = Mb;
  mv.scale = 1.f; mv.coefPtr = coef;
  mmsplit_k<<<dim3(8, 8, 1), 256, 0, stream>>>(mv);

  mconst_k<<<64, 256, 0, stream>>>(Mb, sums, mconst);
  apply_mfma<<<dim3(4, 128), 256, 0, stream>>>(fcb, Mb, mconst, Xc, out);
}